// Round 1
// baseline (126.048 us; speedup 1.0000x reference)
//
#include <hip/hip_runtime.h>
#include <math.h>

// knnLoss: B=4, N=8192, k=3. Brute-force 3-NN, LDS tiles, forced-packed fp32.
// R1: (a) merge kernel re-parallelized 128->512 blocks with 4-way q-split,
//     (b) per-source norm s2 deferred out of the hot loop (selection on
//         p = |t|^2 - 2 s.t is order-equivalent; add s2 before sqrt in merge).
#define BATCH 4
#define NPTS 8192
#define TILE 512            // targets per block tile
#define TSPLIT 16           // NPTS / TILE
#define SRC_PER_BLOCK 512   // 256 threads x 2 sources
#define SRC_CHUNKS 16       // NPTS / SRC_PER_BLOCK
#define NSRC_TOT (BATCH * NPTS)  // 32768
#define QTOT (TSPLIT * 3)   // 48 partial values per source
#define QGROUPS 4
#define QPG (QTOT / QGROUPS)  // 12 per q-group

typedef __attribute__((ext_vector_type(2))) float f2;

// Branchless insert into sorted ascending triple; 4 ops via med3.
__device__ __forceinline__ void insert3(float d, float& a0, float& a1, float& a2) {
    float h = fmaxf(a1, d);
    float m = __builtin_amdgcn_fmed3f(a0, a1, d);
    a2 = fminf(a2, h);
    a1 = m;
    a0 = fminf(a0, d);
}

// Merge two sorted-ascending triples -> the sorted 3 smallest of the union. 6 ops.
__device__ __forceinline__ void merge33(float a0, float a1, float a2,
                                        float& b0, float& b1, float& b2) {
    float s0 = fminf(a0, b0);
    float h  = fmaxf(a0, b0);
    float m  = fminf(a1, b1);
    float mm = fminf(a2, b2);
    b1 = fminf(h, m);
    b2 = __builtin_amdgcn_fmed3f(h, m, mm);
    b0 = s0;
}

__global__ __launch_bounds__(256) void knn_partial(const float* __restrict__ src,
                                                   const float* __restrict__ tgt,
                                                   float* __restrict__ part,
                                                   float* __restrict__ hdr) {
    // Entry e (targets 2e,2e+1): ts[2e]={x0,x1,y0,y1}, ts[2e+1]={z0,z1,w0,w1}
    __shared__ float4 ts[TILE / 2 * 2];
    const int tid = threadIdx.x;
    const int sc = blockIdx.x, tc = blockIdx.y, b = blockIdx.z;

    // Zero the reduction header once (merge runs strictly after this kernel).
    if (sc == 0 && tc == 0 && b == 0 && tid < 16) hdr[tid] = 0.0f;

    {
        const float* tb = tgt + ((size_t)b * NPTS + (size_t)tc * TILE + 2 * tid) * 3;
        float x0 = tb[0], y0 = tb[1], z0 = tb[2];
        float x1 = tb[3], y1 = tb[4], z1 = tb[5];
        float w0 = x0 * x0 + y0 * y0 + z0 * z0;
        float w1 = x1 * x1 + y1 * y1 + z1 * z1;
        if (!(x0 != 0.f || y0 != 0.f || z0 != 0.f)) w0 = 3.0e38f;
        if (!(x1 != 0.f || y1 != 0.f || z1 != 0.f)) w1 = 3.0e38f;
        ts[2 * tid + 0] = make_float4(x0, x1, y0, y1);
        ts[2 * tid + 1] = make_float4(z0, z1, w0, w1);
    }
    __syncthreads();

    // 2 sources per thread, packed precomputes in both halves. (s2 deferred.)
    f2 nx[2], ny[2], nz[2];
    #pragma unroll
    for (int s = 0; s < 2; ++s) {
        int i = sc * SRC_PER_BLOCK + tid + 256 * s;
        const float* sp = src + ((size_t)b * NPTS + i) * 3;
        float ax = sp[0], ay = sp[1], az = sp[2];
        nx[s] = (f2){-2.f * ax, -2.f * ax};
        ny[s] = (f2){-2.f * ay, -2.f * ay};
        nz[s] = (f2){-2.f * az, -2.f * az};
    }

    // 4 independent chains: [source][even/odd target]
    float c0[2][2], c1[2][2], c2[2][2];
    #pragma unroll
    for (int s = 0; s < 2; ++s)
        for (int h = 0; h < 2; ++h) { c0[s][h] = c1[s][h] = c2[s][h] = 3e38f; }

    #pragma unroll 4
    for (int e = 0; e < TILE / 2; ++e) {
        float4 p = ts[2 * e + 0];   // ds_read_b128 (broadcast)
        float4 q = ts[2 * e + 1];
        f2 xs = (f2){p.x, p.y};
        f2 ys = (f2){p.z, p.w};
        f2 zs = (f2){q.x, q.y};
        f2 ws = (f2){q.z, q.w};
        #pragma unroll
        for (int s = 0; s < 2; ++s) {
            // p = |t|^2 - 2 s.t  (3 packed FMAs; s2 added in merge before sqrt)
            f2 acc = __builtin_elementwise_fma(zs, nz[s], ws);  // v_pk_fma_f32
            acc = __builtin_elementwise_fma(ys, ny[s], acc);
            acc = __builtin_elementwise_fma(xs, nx[s], acc);
            insert3(acc.x, c0[s][0], c1[s][0], c2[s][0]);
            insert3(acc.y, c0[s][1], c1[s][1], c2[s][1]);
        }
    }

    // Merge odd chain into even, write sorted triple (coalesced).
    #pragma unroll
    for (int s = 0; s < 2; ++s) {
        merge33(c0[s][1], c1[s][1], c2[s][1], c0[s][0], c1[s][0], c2[s][0]);
        size_t flat = (size_t)b * NPTS + sc * SRC_PER_BLOCK + tid + 256 * s;
        part[((size_t)tc * 3 + 0) * NSRC_TOT + flat] = c0[s][0];
        part[((size_t)tc * 3 + 1) * NSRC_TOT + flat] = c1[s][0];
        part[((size_t)tc * 3 + 2) * NSRC_TOT + flat] = c2[s][0];
    }
}

// 512 blocks x 256 threads laid out [QGROUPS=4][64 lanes]; each thread reduces
// 12 partials for one source, then LDS-merge across the 4 groups.
__global__ __launch_bounds__(256) void knn_merge(const float* __restrict__ src,
                                                 const float* __restrict__ part,
                                                 float* __restrict__ acc,
                                                 float* __restrict__ cnt,
                                                 unsigned* __restrict__ ticket,
                                                 float* __restrict__ out) {
    const int lane = threadIdx.x & 63;
    const int qg = threadIdx.x >> 6;
    const int gid = blockIdx.x * 64 + lane;   // 0 .. NSRC_TOT-1
    const int b = gid >> 13;                  // uniform per block (64 | 8192)

    // 12 independent loads issued up front (deep MLP), 2 ILP chains.
    float v[QPG];
    #pragma unroll
    for (int j = 0; j < QPG; ++j)
        v[j] = part[(size_t)(qg * QPG + j) * NSRC_TOT + gid];

    float t0[2], t1[2], t2[2];
    #pragma unroll
    for (int c = 0; c < 2; ++c) { t0[c] = t1[c] = t2[c] = 3e38f; }
    #pragma unroll
    for (int j = 0; j < QPG; ++j)
        insert3(v[j], t0[j & 1], t1[j & 1], t2[j & 1]);
    merge33(t0[1], t1[1], t2[1], t0[0], t1[0], t2[0]);

    __shared__ float r0[QGROUPS][64], r1[QGROUPS][64], r2[QGROUPS][64];
    r0[qg][lane] = t0[0];
    r1[qg][lane] = t1[0];
    r2[qg][lane] = t2[0];

    // Prefetch source point for the final stage (overlaps the barrier).
    float sx = 0.f, sy = 0.f, sz = 0.f;
    if (threadIdx.x < 64) {
        sx = src[(size_t)gid * 3 + 0];
        sy = src[(size_t)gid * 3 + 1];
        sz = src[(size_t)gid * 3 + 2];
    }
    __syncthreads();

    if (threadIdx.x < 64) {
        float a0 = r0[0][lane], a1 = r1[0][lane], a2 = r2[0][lane];
        #pragma unroll
        for (int g = 1; g < QGROUPS; ++g)
            merge33(r0[g][lane], r1[g][lane], r2[g][lane], a0, a1, a2);

        bool valid = (sx != 0.f) || (sy != 0.f) || (sz != 0.f);
        float q2 = sx * sx + sy * sy + sz * sz;  // deferred |s|^2
        float s = valid ? (sqrtf(fmaxf(a0 + q2, 0.f)) + sqrtf(fmaxf(a1 + q2, 0.f)) +
                           sqrtf(fmaxf(a2 + q2, 0.f)))
                        : 0.f;
        float c = valid ? 1.f : 0.f;

        // Single-wave reduction (the 64 active threads are wave 0).
        for (int off = 32; off >= 1; off >>= 1) {
            s += __shfl_down(s, off);
            c += __shfl_down(c, off);
        }
        if (lane == 0) {
            atomicAdd(&acc[b], s);
            atomicAdd(&cnt[b], c);
            __threadfence();
            unsigned t = atomicAdd(ticket, 1u);
            if (t == (unsigned)(gridDim.x - 1)) {
                float loss = 0.f;
                #pragma unroll
                for (int bb = 0; bb < BATCH; ++bb) {
                    float as = atomicAdd(&acc[bb], 0.f);
                    float ac = atomicAdd(&cnt[bb], 0.f);
                    loss += as / (ac * 3.0f);
                }
                out[0] = loss * (1.0f / BATCH);
            }
        }
    }
}

extern "C" void kernel_launch(void* const* d_in, const int* in_sizes, int n_in,
                              void* d_out, int out_size, void* d_ws, size_t ws_size,
                              hipStream_t stream) {
    const float* src = (const float*)d_in[0];
    const float* tgt = (const float*)d_in[1];
    float* out = (float*)d_out;

    // ws: [0,16) acc[4]; [16,32) cnt[4]; [32,36) ticket; [64) pad; [256,...) partials
    float* hdr = (float*)d_ws;
    float* acc = hdr;
    float* cnt = hdr + 4;
    unsigned* ticket = (unsigned*)((char*)d_ws + 32);
    float* part = (float*)((char*)d_ws + 256);  // 16*3*32768*4 B = 6.29 MB

    dim3 g1(SRC_CHUNKS, TSPLIT, BATCH);  // 16 x 16 x 4 = 1024 blocks
    knn_partial<<<g1, 256, 0, stream>>>(src, tgt, part, hdr);

    knn_merge<<<dim3(NSRC_TOT / 64), 256, 0, stream>>>(src, part, acc, cnt, ticket, out);
}

// Round 3
// 98.775 us; speedup vs baseline: 1.2761x; 1.2761x over previous
//
#include <hip/hip_runtime.h>
#include <math.h>

// knnLoss: B=4, N=8192, k=3. Brute-force 3-NN.
// R3 == R2 resubmitted (R2 bench died with an infra container error; no verdict).
// R2: hierarchical octet-min selection in the partial kernel.
//   - Targets grouped 8-per-octet in LDS (padded to 9 float4 = 144B stride).
//   - Hot loop: 12 pk-FMA + 4 min ops + 1 pack + 1 insert3 per octet per source
//     (~2.75 VALU/pair vs 5.5 before). Octet index packed into low 6 mantissa
//     bits of the octet-min; exact values recomputed in a once-per-tile fixup,
//     so packing perturbs *selection* only (bounded 1e-5 rel., tie cases only).
//   - Containment proof: a true top-3 value's octet must be a top-3 octet by
//     min (else >=3 smaller octet-mins exist, forcing its rank > 3).
//   - Merge is the round-0 128-block structure (+ deferred |s|^2 fix).
#define BATCH 4
#define NPTS 8192
#define TILE 512            // targets per block tile
#define TSPLIT 16           // NPTS / TILE
#define SRC_PER_BLOCK 512   // 256 threads x 2 sources
#define SRC_CHUNKS 16       // NPTS / SRC_PER_BLOCK
#define NSRC_TOT (BATCH * NPTS)  // 32768
#define NOCT (TILE / 8)     // 64 octets per tile
#define OCTF 36             // floats per padded octet (9 float4 = 144 B)

typedef __attribute__((ext_vector_type(2))) float f2;

__device__ __forceinline__ float min3f(float a, float b, float c) {
    float d;
    asm("v_min3_f32 %0, %1, %2, %3" : "=v"(d) : "v"(a), "v"(b), "v"(c));
    return d;
}

// Branchless insert into sorted ascending triple; 4 ops via med3.
__device__ __forceinline__ void insert3(float d, float& a0, float& a1, float& a2) {
    float h = fmaxf(a1, d);
    float m = __builtin_amdgcn_fmed3f(a0, a1, d);
    a2 = fminf(a2, h);
    a1 = m;
    a0 = fminf(a0, d);
}

// Merge two sorted-ascending triples -> the sorted 3 smallest of the union. 6 ops.
__device__ __forceinline__ void merge33(float a0, float a1, float a2,
                                        float& b0, float& b1, float& b2) {
    float s0 = fminf(a0, b0);
    float h  = fmaxf(a0, b0);
    float m  = fminf(a1, b1);
    float mm = fminf(a2, b2);
    b1 = fminf(h, m);
    b2 = __builtin_amdgcn_fmed3f(h, m, mm);
    b0 = s0;
}

// Recompute the 8 exact p-values of one octet and insert into the exact chain.
__device__ __forceinline__ void octet_insert(const float4* ob, f2 nx, f2 ny, f2 nz,
                                             float& c0, float& c1, float& c2) {
    float4 X0 = ob[0], X1 = ob[1], Y0 = ob[2], Y1 = ob[3];
    float4 Z0 = ob[4], Z1 = ob[5], W0 = ob[6], W1 = ob[7];
    f2 pa = __builtin_elementwise_fma((f2){Z0.x, Z0.y}, nz, (f2){W0.x, W0.y});
    pa = __builtin_elementwise_fma((f2){Y0.x, Y0.y}, ny, pa);
    pa = __builtin_elementwise_fma((f2){X0.x, X0.y}, nx, pa);
    f2 pb = __builtin_elementwise_fma((f2){Z0.z, Z0.w}, nz, (f2){W0.z, W0.w});
    pb = __builtin_elementwise_fma((f2){Y0.z, Y0.w}, ny, pb);
    pb = __builtin_elementwise_fma((f2){X0.z, X0.w}, nx, pb);
    f2 pc = __builtin_elementwise_fma((f2){Z1.x, Z1.y}, nz, (f2){W1.x, W1.y});
    pc = __builtin_elementwise_fma((f2){Y1.x, Y1.y}, ny, pc);
    pc = __builtin_elementwise_fma((f2){X1.x, X1.y}, nx, pc);
    f2 pd = __builtin_elementwise_fma((f2){Z1.z, Z1.w}, nz, (f2){W1.z, W1.w});
    pd = __builtin_elementwise_fma((f2){Y1.z, Y1.w}, ny, pd);
    pd = __builtin_elementwise_fma((f2){X1.z, X1.w}, nx, pd);
    insert3(pa.x, c0, c1, c2);
    insert3(pa.y, c0, c1, c2);
    insert3(pb.x, c0, c1, c2);
    insert3(pb.y, c0, c1, c2);
    insert3(pc.x, c0, c1, c2);
    insert3(pc.y, c0, c1, c2);
    insert3(pd.x, c0, c1, c2);
    insert3(pd.y, c0, c1, c2);
}

__global__ __launch_bounds__(256) void knn_partial(const float* __restrict__ src,
                                                   const float* __restrict__ tgt,
                                                   float* __restrict__ part,
                                                   float* __restrict__ hdr) {
    // Octet o, slot k: x_k at float 36o + 4*(k>>2) + (k&3); y +8; z +16; w +24.
    __shared__ float tsf[NOCT * OCTF];  // 9216 B
    const int tid = threadIdx.x;
    const int sc = blockIdx.x, tc = blockIdx.y, b = blockIdx.z;

    // Zero the reduction header once (merge runs strictly after this kernel).
    if (sc == 0 && tc == 0 && b == 0 && tid < 16) hdr[tid] = 0.0f;

    {
        const float* tb = tgt + ((size_t)b * NPTS + (size_t)tc * TILE + 2 * tid) * 3;
        float x0 = tb[0], y0 = tb[1], z0 = tb[2];
        float x1 = tb[3], y1 = tb[4], z1 = tb[5];
        float w0 = x0 * x0 + y0 * y0 + z0 * z0;
        float w1 = x1 * x1 + y1 * y1 + z1 * z1;
        if (!(x0 != 0.f || y0 != 0.f || z0 != 0.f)) w0 = 3.0e38f;
        if (!(x1 != 0.f || y1 != 0.f || z1 != 0.f)) w1 = 3.0e38f;
        int o = tid >> 2;
        int k = (2 * tid) & 7;  // even -> k and k+1 share the 4-group
        int base = o * OCTF + ((k >> 2) << 2) + (k & 3);
        *(float2*)(tsf + base)      = make_float2(x0, x1);
        *(float2*)(tsf + base + 8)  = make_float2(y0, y1);
        *(float2*)(tsf + base + 16) = make_float2(z0, z1);
        *(float2*)(tsf + base + 24) = make_float2(w0, w1);
    }
    __syncthreads();

    // 2 sources per thread, packed precomputes. (|s|^2 deferred to merge.)
    f2 nx[2], ny[2], nz[2];
    #pragma unroll
    for (int s = 0; s < 2; ++s) {
        int i = sc * SRC_PER_BLOCK + tid + 256 * s;
        const float* sp = src + ((size_t)b * NPTS + i) * 3;
        float ax = sp[0], ay = sp[1], az = sp[2];
        nx[s] = (f2){-2.f * ax, -2.f * ax};
        ny[s] = (f2){-2.f * ay, -2.f * ay};
        nz[s] = (f2){-2.f * az, -2.f * az};
    }

    // Candidate chain per source: packed (octet-min | octet-idx), ascending.
    float q0[2], q1[2], q2c[2];
    #pragma unroll
    for (int s = 0; s < 2; ++s) { q0[s] = q1[s] = q2c[s] = 3e38f; }

    const float4* tsv = (const float4*)tsf;
    #pragma unroll 2
    for (int o = 0; o < NOCT; ++o) {
        float4 X0 = tsv[9 * o + 0], X1 = tsv[9 * o + 1];  // broadcast ds_read_b128
        float4 Y0 = tsv[9 * o + 2], Y1 = tsv[9 * o + 3];
        float4 Z0 = tsv[9 * o + 4], Z1 = tsv[9 * o + 5];
        float4 W0 = tsv[9 * o + 6], W1 = tsv[9 * o + 7];
        #pragma unroll
        for (int s = 0; s < 2; ++s) {
            f2 pa = __builtin_elementwise_fma((f2){Z0.x, Z0.y}, nz[s], (f2){W0.x, W0.y});
            pa = __builtin_elementwise_fma((f2){Y0.x, Y0.y}, ny[s], pa);
            pa = __builtin_elementwise_fma((f2){X0.x, X0.y}, nx[s], pa);
            f2 pb = __builtin_elementwise_fma((f2){Z0.z, Z0.w}, nz[s], (f2){W0.z, W0.w});
            pb = __builtin_elementwise_fma((f2){Y0.z, Y0.w}, ny[s], pb);
            pb = __builtin_elementwise_fma((f2){X0.z, X0.w}, nx[s], pb);
            f2 pc = __builtin_elementwise_fma((f2){Z1.x, Z1.y}, nz[s], (f2){W1.x, W1.y});
            pc = __builtin_elementwise_fma((f2){Y1.x, Y1.y}, ny[s], pc);
            pc = __builtin_elementwise_fma((f2){X1.x, X1.y}, nx[s], pc);
            f2 pd = __builtin_elementwise_fma((f2){Z1.z, Z1.w}, nz[s], (f2){W1.z, W1.w});
            pd = __builtin_elementwise_fma((f2){Y1.z, Y1.w}, ny[s], pd);
            pd = __builtin_elementwise_fma((f2){X1.z, X1.w}, nx[s], pd);
            float m1 = min3f(pa.x, pa.y, pb.x);
            float m2 = min3f(pb.y, pc.x, pc.y);
            float m3 = min3f(pd.x, pd.y, m1);
            float m4 = fminf(m2, m3);
            unsigned u = (__float_as_uint(m4) & 0xFFFFFFC0u) | (unsigned)o;
            insert3(__uint_as_float(u), q0[s], q1[s], q2c[s]);
        }
    }

    // Fixup: exact recompute of the <=3 candidate octets per source.
    #pragma unroll
    for (int s = 0; s < 2; ++s) {
        float c0 = 3e38f, c1 = 3e38f, c2 = 3e38f;
        int o0 = (int)(__float_as_uint(q0[s]) & 63u);
        int o1 = (int)(__float_as_uint(q1[s]) & 63u);
        int o2 = (int)(__float_as_uint(q2c[s]) & 63u);
        octet_insert(tsv + 9 * o0, nx[s], ny[s], nz[s], c0, c1, c2);
        octet_insert(tsv + 9 * o1, nx[s], ny[s], nz[s], c0, c1, c2);
        octet_insert(tsv + 9 * o2, nx[s], ny[s], nz[s], c0, c1, c2);
        size_t flat = (size_t)b * NPTS + sc * SRC_PER_BLOCK + tid + 256 * s;
        part[((size_t)tc * 3 + 0) * NSRC_TOT + flat] = c0;
        part[((size_t)tc * 3 + 1) * NSRC_TOT + flat] = c1;
        part[((size_t)tc * 3 + 2) * NSRC_TOT + flat] = c2;
    }
}

// Round-0 merge structure (128 blocks x 256 threads), with deferred |s|^2.
__global__ __launch_bounds__(256) void knn_merge(const float* __restrict__ src,
                                                 const float* __restrict__ part,
                                                 float* __restrict__ acc,
                                                 float* __restrict__ cnt,
                                                 unsigned* __restrict__ ticket,
                                                 float* __restrict__ out) {
    const int gid = blockIdx.x * 256 + threadIdx.x;  // 0 .. NSRC_TOT-1
    const int b = gid >> 13;                         // uniform per block

    // 48 partial values -> 4 independent sub-triples (ILP), then merge tree.
    float t0[4], t1[4], t2[4];
    #pragma unroll
    for (int c = 0; c < 4; ++c) { t0[c] = t1[c] = t2[c] = 3e38f; }
    #pragma unroll
    for (int q = 0; q < TSPLIT * 3; ++q)
        insert3(part[(size_t)q * NSRC_TOT + gid], t0[q & 3], t1[q & 3], t2[q & 3]);
    merge33(t0[1], t1[1], t2[1], t0[0], t1[0], t2[0]);
    merge33(t0[3], t1[3], t2[3], t0[2], t1[2], t2[2]);
    merge33(t0[2], t1[2], t2[2], t0[0], t1[0], t2[0]);

    float sx = src[(size_t)gid * 3 + 0];
    float sy = src[(size_t)gid * 3 + 1];
    float sz = src[(size_t)gid * 3 + 2];
    bool valid = (sx != 0.f) || (sy != 0.f) || (sz != 0.f);
    float qq = sx * sx + sy * sy + sz * sz;  // deferred |s|^2
    float s = valid ? (sqrtf(fmaxf(t0[0] + qq, 0.f)) + sqrtf(fmaxf(t1[0] + qq, 0.f)) +
                       sqrtf(fmaxf(t2[0] + qq, 0.f)))
                    : 0.f;
    float c = valid ? 1.f : 0.f;

    for (int off = 32; off >= 1; off >>= 1) {
        s += __shfl_down(s, off);
        c += __shfl_down(c, off);
    }
    __shared__ float red_s[4], red_c[4];
    int wave = threadIdx.x >> 6, lane = threadIdx.x & 63;
    if (lane == 0) { red_s[wave] = s; red_c[wave] = c; }
    __syncthreads();
    if (threadIdx.x == 0) {
        atomicAdd(&acc[b], red_s[0] + red_s[1] + red_s[2] + red_s[3]);
        atomicAdd(&cnt[b], red_c[0] + red_c[1] + red_c[2] + red_c[3]);
        __threadfence();
        unsigned t = atomicAdd(ticket, 1u);
        if (t == (unsigned)(gridDim.x - 1)) {
            float loss = 0.f;
            #pragma unroll
            for (int bb = 0; bb < BATCH; ++bb) {
                float as = atomicAdd(&acc[bb], 0.f);
                float ac = atomicAdd(&cnt[bb], 0.f);
                loss += as / (ac * 3.0f);
            }
            out[0] = loss * (1.0f / BATCH);
        }
    }
}

extern "C" void kernel_launch(void* const* d_in, const int* in_sizes, int n_in,
                              void* d_out, int out_size, void* d_ws, size_t ws_size,
                              hipStream_t stream) {
    const float* src = (const float*)d_in[0];
    const float* tgt = (const float*)d_in[1];
    float* out = (float*)d_out;

    // ws: [0,16) acc[4]; [16,32) cnt[4]; [32,36) ticket; [64) pad; [256,...) partials
    float* hdr = (float*)d_ws;
    float* acc = hdr;
    float* cnt = hdr + 4;
    unsigned* ticket = (unsigned*)((char*)d_ws + 32);
    float* part = (float*)((char*)d_ws + 256);  // 16*3*32768*4 B = 6.29 MB

    dim3 g1(SRC_CHUNKS, TSPLIT, BATCH);  // 16 x 16 x 4 = 1024 blocks
    knn_partial<<<g1, 256, 0, stream>>>(src, tgt, part, hdr);

    knn_merge<<<dim3(NSRC_TOT / 256), 256, 0, stream>>>(src, part, acc, cnt, ticket, out);
}